// Round 1
// baseline (7048.357 us; speedup 1.0000x reference)
//
#include <hip/hip_runtime.h>
#include <hip/hip_bf16.h>

// SolvGNNV6: two-sided GNN (cation/anion) + MLP head. fp32 baseline.
// Pipeline per side:
//   deg count (int atomics) -> rsqrt norms -> exclusive scan -> CSR fill
//   -> gather-aggregate (deterministic) -> SGEMM w/ fused row-scale+bias+act
// Then pool (40 nodes/graph, contiguous n2g) -> MLP (2 SGEMM + wave-GEMV).

#define N_NODES 81920
#define N_EDGES 327680
#define N_GRAPHS 2048
#define HDIM 256
#define INDIM 74
#define ZDIM 520   // 2*256 + 8

// ---------------- degree / norm ----------------
__global__ void count_deg_kernel(const int* __restrict__ src, const int* __restrict__ dst,
                                 int* __restrict__ dout, int* __restrict__ din, int E) {
    int e = blockIdx.x * blockDim.x + threadIdx.x;
    if (e < E) {
        atomicAdd(&dout[src[e]], 1);
        atomicAdd(&din[dst[e]], 1);
    }
}

__global__ void rsqrt_deg_kernel(const int* __restrict__ dout, const int* __restrict__ din,
                                 float* __restrict__ rso, float* __restrict__ rsi, int n) {
    int i = blockIdx.x * blockDim.x + threadIdx.x;
    if (i < n) {
        rso[i] = rsqrtf((float)(dout[i] > 1 ? dout[i] : 1));
        rsi[i] = rsqrtf((float)(din[i] > 1 ? din[i] : 1));
    }
}

// single-block exclusive scan over n elements (n multiple of 1024 not required)
__global__ __launch_bounds__(1024) void scan_excl_kernel(const int* __restrict__ deg,
                                                         int* __restrict__ row_ptr, int n) {
    __shared__ int buf[1024];
    __shared__ int carry;
    int t = threadIdx.x;
    if (t == 0) carry = 0;
    __syncthreads();
    for (int base = 0; base < n; base += 1024) {
        int v = (base + t < n) ? deg[base + t] : 0;
        buf[t] = v;
        __syncthreads();
        for (int off = 1; off < 1024; off <<= 1) {
            int x = (t >= off) ? buf[t - off] : 0;
            __syncthreads();
            buf[t] += x;
            __syncthreads();
        }
        if (base + t < n) row_ptr[base + t] = carry + buf[t] - v;  // exclusive
        __syncthreads();
        if (t == 0) carry += buf[1023];
        __syncthreads();
    }
    if (t == 0) row_ptr[n] = carry;
}

__global__ void csr_fill_kernel(const int* __restrict__ src, const int* __restrict__ dst,
                                const int* __restrict__ rp, int* __restrict__ cursor,
                                int* __restrict__ csr, int E) {
    int e = blockIdx.x * blockDim.x + threadIdx.x;
    if (e < E) {
        int d = dst[e];
        int p = atomicAdd(&cursor[d], 1);
        csr[rp[d] + p] = src[e];
    }
}

// ---------------- aggregation: agg[n,f] = sum_{s in in(n)} h[s,f]*rs_out[s] ----
__global__ void gather_agg_kernel(const float* __restrict__ h, const int* __restrict__ csr,
                                  const int* __restrict__ rp, const float* __restrict__ rs_out,
                                  float* __restrict__ agg, int D) {
    int node = blockIdx.x;
    int f = threadIdx.x;
    if (f >= D) return;
    int s = rp[node], e = rp[node + 1];
    float acc = 0.f;
    for (int j = s; j < e; ++j) {
        int sn = csr[j];
        acc += h[(long)sn * D + f] * rs_out[sn];
    }
    agg[(long)node * D + f] = acc;
}

// ---------------- SGEMM: C = act(rowscale(A) @ W + bias) ----------------
// A: M x K row-major, W: K x N row-major, C: M x N. M%64==0, N%64==0. K ragged ok.
// act: 0 none, 1 relu, 2 leaky(0.01)
#define BM 64
#define BN 64
#define BK 16
__global__ __launch_bounds__(256) void gemm_rowscale_kernel(
        const float* __restrict__ A, const float* __restrict__ rs,
        const float* __restrict__ W, const float* __restrict__ bias,
        float* __restrict__ C, int M, int N, int K, int act) {
    __shared__ float As[BK][BM + 1];
    __shared__ float Bs[BK][BN];
    int bm = blockIdx.x, bn = blockIdx.y;
    int t = threadIdx.x;
    int tx = t & 15, ty = t >> 4;
    int row0 = bm * BM, col0 = bn * BN;
    int ra = t >> 2;          // 0..63 : A row within tile
    int ka = (t & 3) * 4;     // 0,4,8,12
    int kb = t >> 4;          // 0..15 : B k within tile
    int nb = (t & 15) * 4;    // 0..60
    float rscale = rs ? rs[row0 + ra] : 1.f;
    float acc[4][4] = {};
    for (int k0 = 0; k0 < K; k0 += BK) {
#pragma unroll
        for (int i = 0; i < 4; ++i) {
            int k = k0 + ka + i;
            As[ka + i][ra] = (k < K) ? A[(long)(row0 + ra) * K + k] * rscale : 0.f;
        }
#pragma unroll
        for (int j = 0; j < 4; ++j) {
            int k = k0 + kb;
            Bs[kb][nb + j] = (k < K) ? W[(long)k * N + col0 + nb + j] : 0.f;
        }
        __syncthreads();
#pragma unroll
        for (int kk = 0; kk < BK; ++kk) {
            float a[4], b[4];
#pragma unroll
            for (int i = 0; i < 4; ++i) a[i] = As[kk][ty * 4 + i];
#pragma unroll
            for (int j = 0; j < 4; ++j) b[j] = Bs[kk][tx * 4 + j];
#pragma unroll
            for (int i = 0; i < 4; ++i)
#pragma unroll
                for (int j = 0; j < 4; ++j) acc[i][j] += a[i] * b[j];
        }
        __syncthreads();
    }
#pragma unroll
    for (int i = 0; i < 4; ++i) {
        int r = row0 + ty * 4 + i;
#pragma unroll
        for (int j = 0; j < 4; ++j) {
            int c = col0 + tx * 4 + j;
            float v = acc[i][j] + bias[c];
            if (act == 1) v = fmaxf(v, 0.f);
            else if (act == 2) v = (v > 0.f) ? v : 0.01f * v;
            C[(long)r * N + c] = v;
        }
    }
}

// ---------------- pooling: z[g, zoff+f] = sum_{j<40} h[g*40+j, f] ----------------
__global__ void pool_sum_kernel(const float* __restrict__ h, float* __restrict__ z, int zoff) {
    int g = blockIdx.x;
    int f = threadIdx.x;  // 256
    float acc = 0.f;
    const float* base = h + (long)g * 40 * HDIM + f;
#pragma unroll
    for (int j = 0; j < 40; ++j) acc += base[j * HDIM];
    z[(long)g * ZDIM + zoff + f] = acc;
}

__global__ void copy_add_kernel(const float* __restrict__ add, float* __restrict__ z) {
    int i = blockIdx.x * blockDim.x + threadIdx.x;
    if (i < N_GRAPHS * 8) {
        int g = i >> 3, a = i & 7;
        z[(long)g * ZDIM + 512 + a] = add[i];
    }
}

// ---------------- final GEMV: out[r] = A[r,:] . w + b ----------------
__global__ void gemv_out_kernel(const float* __restrict__ A, const float* __restrict__ w,
                                const float* __restrict__ b, float* __restrict__ out, int K) {
    int wave = threadIdx.x >> 6;
    int lane = threadIdx.x & 63;
    int row = blockIdx.x * 4 + wave;
    float acc = 0.f;
    for (int k = lane; k < K; k += 64) acc += A[(long)row * K + k] * w[k];
#pragma unroll
    for (int off = 32; off > 0; off >>= 1) acc += __shfl_down(acc, off, 64);
    if (lane == 0) out[row] = acc + b[0];
}

extern "C" void kernel_launch(void* const* d_in, const int* in_sizes, int n_in,
                              void* d_out, int out_size, void* d_ws, size_t ws_size,
                              hipStream_t stream) {
    const int N = N_NODES, E = N_EDGES, B = N_GRAPHS;

    const int*   cat_src = (const int*)d_in[0];
    const int*   cat_dst = (const int*)d_in[1];
    const float* cat_x   = (const float*)d_in[3];
    const int*   an_src  = (const int*)d_in[4];
    const int*   an_dst  = (const int*)d_in[5];
    const float* an_x    = (const float*)d_in[7];
    const float* add_f   = (const float*)d_in[8];
    const float* W0      = (const float*)d_in[9];
    const float* b0      = (const float*)d_in[10];
    const float* gcrW    = (const float*)d_in[11];
    const float* gcrb    = (const float*)d_in[12];
    const float* mW1     = (const float*)d_in[13];
    const float* mb1     = (const float*)d_in[14];
    const float* mW2     = (const float*)d_in[15];
    const float* mb2     = (const float*)d_in[16];
    const float* mW3     = (const float*)d_in[17];
    const float* mb3     = (const float*)d_in[18];
    float* out = (float*)d_out;

    // ---- workspace carve (~188 MB) ----
    char* p = (char*)d_ws;
    auto alloc = [&](size_t bytes) -> void* {
        void* r = (void*)p;
        p += (bytes + 255) & ~(size_t)255;
        return r;
    };
    int*   deg_o   = (int*)alloc((size_t)N * 4);
    int*   deg_i   = (int*)alloc((size_t)N * 4);
    int*   row_ptr = (int*)alloc((size_t)(N + 1) * 4);
    int*   cursor  = (int*)alloc((size_t)N * 4);
    int*   csr     = (int*)alloc((size_t)E * 4);
    float* rs_o    = (float*)alloc((size_t)N * 4);
    float* rs_i    = (float*)alloc((size_t)N * 4);
    float* hA      = (float*)alloc((size_t)N * HDIM * 4);
    float* hB      = (float*)alloc((size_t)N * HDIM * 4);
    float* z       = (float*)alloc((size_t)B * ZDIM * 4);
    float* m1      = (float*)alloc((size_t)B * 1024 * 4);
    float* m2      = (float*)alloc((size_t)B * 512 * 4);
    (void)ws_size; (void)in_sizes; (void)n_in; (void)out_size;

    auto run_side = [&](const int* src, const int* dst, const float* x, int zoff) {
        hipMemsetAsync(deg_o, 0, (size_t)N * 4, stream);
        hipMemsetAsync(deg_i, 0, (size_t)N * 4, stream);
        hipMemsetAsync(cursor, 0, (size_t)N * 4, stream);
        count_deg_kernel<<<E / 256, 256, 0, stream>>>(src, dst, deg_o, deg_i, E);
        rsqrt_deg_kernel<<<N / 256, 256, 0, stream>>>(deg_o, deg_i, rs_o, rs_i, N);
        scan_excl_kernel<<<1, 1024, 0, stream>>>(deg_i, row_ptr, N);
        csr_fill_kernel<<<E / 256, 256, 0, stream>>>(src, dst, row_ptr, cursor, csr, E);

        // first conv: x (N x 74) -> hA (N x 256), no activation
        gather_agg_kernel<<<N, 128, 0, stream>>>(x, csr, row_ptr, rs_o, hB, INDIM);
        gemm_rowscale_kernel<<<dim3(N / BM, HDIM / BN), 256, 0, stream>>>(
            hB, rs_i, W0, b0, hA, N, HDIM, INDIM, 0);

        // 5 GCR layers x 2 convs, relu fused into each gemm epilogue
        for (int l = 0; l < 5; ++l) {
            for (int j = 0; j < 2; ++j) {
                gather_agg_kernel<<<N, HDIM, 0, stream>>>(hA, csr, row_ptr, rs_o, hB, HDIM);
                gemm_rowscale_kernel<<<dim3(N / BM, HDIM / BN), 256, 0, stream>>>(
                    hB, rs_i, gcrW + (size_t)(l * 2 + j) * HDIM * HDIM,
                    gcrb + (size_t)(l * 2 + j) * HDIM, hA, N, HDIM, HDIM, 1);
            }
        }
        pool_sum_kernel<<<B, HDIM, 0, stream>>>(hA, z, zoff);
    };

    run_side(cat_src, cat_dst, cat_x, 0);
    run_side(an_src, an_dst, an_x, HDIM);
    copy_add_kernel<<<(B * 8 + 255) / 256, 256, 0, stream>>>(add_f, z);

    // MLP head
    gemm_rowscale_kernel<<<dim3(B / BM, 1024 / BN), 256, 0, stream>>>(
        z, nullptr, mW1, mb1, m1, B, 1024, ZDIM, 2);
    gemm_rowscale_kernel<<<dim3(B / BM, 512 / BN), 256, 0, stream>>>(
        m1, nullptr, mW2, mb2, m2, B, 512, 1024, 2);
    gemv_out_kernel<<<B / 4, 256, 0, stream>>>(m2, mW3, mb3, out, 512);
}

// Round 2
// 1807.131 us; speedup vs baseline: 3.9003x; 3.9003x over previous
//
#include <hip/hip_runtime.h>

// SolvGNNV6 round 2: bf16-MFMA conv GEMMs (m97-style), bucketed aggregation,
// fp32 MLP head. Activations bf16 (stored as u16 bits), accumulation fp32.

#define NN 81920     // nodes
#define NE 327680    // edges
#define NB 2048      // graphs
#define H 256
#define INDIM 74
#define KPAD 128     // first-conv K padded 74 -> 128
#define ZD 520       // 2*H + 8
#define DEGCAP 32    // max in-degree bucket (Poisson(4); P(>32) ~ 1e-19)

typedef unsigned short u16;
typedef __attribute__((ext_vector_type(8))) short short8;  // 8 bf16 (4 VGPRs)
typedef __attribute__((ext_vector_type(4))) float f32x4;

__device__ inline u16 f2b(float f) {  // fp32 -> bf16 bits, RNE
    unsigned u = __builtin_bit_cast(unsigned, f);
    u += 0x7fffu + ((u >> 16) & 1u);
    return (u16)(u >> 16);
}
__device__ inline float b2f(u16 b) {
    unsigned u = ((unsigned)b) << 16;
    return __builtin_bit_cast(float, u);
}
__device__ inline float blo(unsigned u) { return __builtin_bit_cast(float, u << 16); }
__device__ inline float bhi(unsigned u) { return __builtin_bit_cast(float, u & 0xffff0000u); }

// ---------- degree count + bucket fill (replaces scan+CSR) ----------
__global__ void fill_kernel(const int* __restrict__ src, const int* __restrict__ dst,
                            int* __restrict__ dego, int* __restrict__ cnti,
                            int* __restrict__ bucket) {
    int e = blockIdx.x * 256 + threadIdx.x;
    if (e < NE) {
        int s = src[e], d = dst[e];
        atomicAdd(&dego[s], 1);
        int p = atomicAdd(&cnti[d], 1);
        if (p < DEGCAP) bucket[d * DEGCAP + p] = s;
    }
}

__global__ void rsqrt_kernel(const int* __restrict__ dego, const int* __restrict__ cnti,
                             float* __restrict__ rso, float* __restrict__ rsi) {
    int i = blockIdx.x * 256 + threadIdx.x;
    if (i < NN) {
        rso[i] = rsqrtf((float)(dego[i] > 1 ? dego[i] : 1));
        rsi[i] = rsqrtf((float)(cnti[i] > 1 ? cnti[i] : 1));
    }
}

// ---------- first-conv aggregation: fp32 x (74) -> bf16 agg (pad to 128) ----------
__global__ __launch_bounds__(128) void gather_x_kernel(
        const float* __restrict__ x, const int* __restrict__ bucket,
        const int* __restrict__ cnti, const float* __restrict__ rso,
        const float* __restrict__ rsi, u16* __restrict__ out) {
    int node = blockIdx.x;
    int f = threadIdx.x;
    int deg = cnti[node]; if (deg > DEGCAP) deg = DEGCAP;
    float acc = 0.f;
    if (f < INDIM) {
        for (int j = 0; j < deg; ++j) {
            int sn = bucket[node * DEGCAP + j];
            acc += x[(size_t)sn * INDIM + f] * rso[sn];
        }
    }
    out[(size_t)node * KPAD + f] = f2b(acc * rsi[node]);
}

// ---------- H-dim aggregation: bf16 h -> bf16 agg, both norms folded ----------
__global__ __launch_bounds__(256) void gather_h_kernel(
        const u16* __restrict__ h, const int* __restrict__ bucket,
        const int* __restrict__ cnti, const float* __restrict__ rso,
        const float* __restrict__ rsi, u16* __restrict__ out) {
    int node = blockIdx.x * 8 + (threadIdx.x >> 5);
    int fc = (threadIdx.x & 31) * 8;     // 8 bf16 = 16 B per thread
    int deg = cnti[node]; if (deg > DEGCAP) deg = DEGCAP;
    float acc[8] = {};
    for (int j = 0; j < deg; ++j) {
        int sn = bucket[node * DEGCAP + j];
        float w = rso[sn];
        uint4 v = *(const uint4*)(h + (size_t)sn * H + fc);
        acc[0] += blo(v.x) * w; acc[1] += bhi(v.x) * w;
        acc[2] += blo(v.y) * w; acc[3] += bhi(v.y) * w;
        acc[4] += blo(v.z) * w; acc[5] += bhi(v.z) * w;
        acc[6] += blo(v.w) * w; acc[7] += bhi(v.w) * w;
    }
    float ri = rsi[node];
    u16 o[8];
#pragma unroll
    for (int i = 0; i < 8; ++i) o[i] = f2b(acc[i] * ri);
    uint4 ov;
    ov.x = o[0] | ((unsigned)o[1] << 16);
    ov.y = o[2] | ((unsigned)o[3] << 16);
    ov.z = o[4] | ((unsigned)o[5] << 16);
    ov.w = o[6] | ((unsigned)o[7] << 16);
    *(uint4*)(out + (size_t)node * H + fc) = ov;
}

// ---------- weight prep: fp32 row-major -> bf16 transposed (N-major, K-contig) ----------
__global__ void prep_w0_kernel(const float* __restrict__ W0, u16* __restrict__ Wt0) {
    int i = blockIdx.x * 256 + threadIdx.x;  // 256*128
    int n = i >> 7, k = i & 127;
    float v = (k < INDIM) ? W0[(size_t)k * H + n] : 0.f;
    Wt0[i] = f2b(v);
}

__global__ void prep_gcr_kernel(const float* __restrict__ W, u16* __restrict__ Wt) {
    int i = blockIdx.x * 256 + threadIdx.x;  // 65536 per layer
    int l = blockIdx.y;                      // 0..9
    int n = i >> 8, k = i & 255;
    Wt[(size_t)l * 65536 + i] = f2b(W[(size_t)l * 65536 + (size_t)k * H + n]);
}

// ---------- bf16 MFMA NT-GEMM: C[M,256] = act(A @ Bt^T + bias) ----------
// A: M x K bf16 (row-major, lda), Bt: 256 x K bf16 (row-major, ldb = K).
// BM=BN=128, BK=32. 256 threads = 4 waves (2x2), each wave 64x64 (4x4 MFMA tiles).
__device__ inline void ldg_lds16(const u16* g, u16* l) {
    __builtin_amdgcn_global_load_lds(
        (const __attribute__((address_space(1))) unsigned int*)g,
        (__attribute__((address_space(3))) unsigned int*)l, 16, 0, 0);
}

__global__ __launch_bounds__(256) void gemm_mfma_kernel(
        const u16* __restrict__ A, int lda,
        const u16* __restrict__ Bt, int ldb,
        const float* __restrict__ bias, u16* __restrict__ C,
        int Kiters, int act) {
    __shared__ u16 As[4096];   // 128 rows x 32 bf16 (64 B/row), 8 KB
    __shared__ u16 Bs[4096];
    int t = threadIdx.x;
    int wave = t >> 6, lane = t & 63;
    int wr = wave >> 1, wc = wave & 1;
    int row0 = blockIdx.x * 128, col0 = blockIdx.y * 128;

    // staging: linear byte offset o = chunk*4096 + t*16; row = o>>6, kbyte = o&63
    int r = t >> 2;            // 0..63
    int kq = (t & 3) * 8;      // element offset within BK=32
    const u16* Ag0 = A + (size_t)(row0 + r) * lda + kq;
    const u16* Ag1 = A + (size_t)(row0 + 64 + r) * lda + kq;
    const u16* Bg0 = Bt + (size_t)(col0 + r) * ldb + kq;
    const u16* Bg1 = Bt + (size_t)(col0 + 64 + r) * ldb + kq;
    u16* AsW = As + wave * 512;  // wave-uniform LDS base (HW adds lane*16)
    u16* BsW = Bs + wave * 512;

    f32x4 acc[4][4] = {};
    int mrow = lane & 15;
    int koff = (lane >> 4) * 8;

    for (int kt = 0; kt < Kiters; ++kt) {
        ldg_lds16(Ag0, AsW);
        ldg_lds16(Ag1, AsW + 2048);
        ldg_lds16(Bg0, BsW);
        ldg_lds16(Bg1, BsW + 2048);
        __syncthreads();   // drains vmcnt (global_load_lds) + lgkm
        short8 a[4], b[4];
#pragma unroll
        for (int mt = 0; mt < 4; ++mt)
            a[mt] = *(const short8*)(As + (size_t)(wr * 64 + mt * 16 + mrow) * 32 + koff);
#pragma unroll
        for (int nt = 0; nt < 4; ++nt)
            b[nt] = *(const short8*)(Bs + (size_t)(wc * 64 + nt * 16 + mrow) * 32 + koff);
#pragma unroll
        for (int mt = 0; mt < 4; ++mt)
#pragma unroll
            for (int nt = 0; nt < 4; ++nt)
                acc[mt][nt] = __builtin_amdgcn_mfma_f32_16x16x32_bf16(
                    a[mt], b[nt], acc[mt][nt], 0, 0, 0);
        __syncthreads();
        Ag0 += 32; Ag1 += 32; Bg0 += 32; Bg1 += 32;
    }

    // epilogue: C/D layout col=lane&15, row=(lane>>4)*4+reg (m89-verified)
#pragma unroll
    for (int mt = 0; mt < 4; ++mt) {
        int rb = row0 + wr * 64 + mt * 16 + (lane >> 4) * 4;
#pragma unroll
        for (int nt = 0; nt < 4; ++nt) {
            int c = col0 + wc * 64 + nt * 16 + (lane & 15);
            float bv = bias[c];
#pragma unroll
            for (int q = 0; q < 4; ++q) {
                float v = acc[mt][nt][q] + bv;
                if (act == 1) v = fmaxf(v, 0.f);
                C[(size_t)(rb + q) * H + c] = f2b(v);
            }
        }
    }
}

// ---------- pooling: sum 40 bf16 rows -> fp32 z ----------
__global__ __launch_bounds__(256) void pool_kernel(const u16* __restrict__ h,
                                                   float* __restrict__ z, int zoff) {
    int g = blockIdx.x, f = threadIdx.x;
    float acc = 0.f;
    const u16* base = h + (size_t)g * 40 * H + f;
#pragma unroll
    for (int j = 0; j < 40; ++j) acc += b2f(base[j * H]);
    z[(size_t)g * ZD + zoff + f] = acc;
}

__global__ void copy_add_kernel(const float* __restrict__ add, float* __restrict__ z) {
    int i = blockIdx.x * 256 + threadIdx.x;
    if (i < NB * 8) {
        int g = i >> 3, a = i & 7;
        z[(size_t)g * ZD + 512 + a] = add[i];
    }
}

// ---------- fp32 tiled SGEMM for MLP head (kept from round 1) ----------
#define BM 64
#define BN 64
#define BK 16
__global__ __launch_bounds__(256) void gemm_f32_kernel(
        const float* __restrict__ A, const float* __restrict__ W,
        const float* __restrict__ bias, float* __restrict__ C,
        int M, int N, int K, int act) {
    __shared__ float Asm[BK][BM + 1];
    __shared__ float Bsm[BK][BN];
    int bm = blockIdx.x, bn = blockIdx.y;
    int t = threadIdx.x;
    int tx = t & 15, ty = t >> 4;
    int row0 = bm * BM, col0 = bn * BN;
    int ra = t >> 2;
    int ka = (t & 3) * 4;
    int kb = t >> 4;
    int nb = (t & 15) * 4;
    float acc[4][4] = {};
    for (int k0 = 0; k0 < K; k0 += BK) {
#pragma unroll
        for (int i = 0; i < 4; ++i) {
            int k = k0 + ka + i;
            Asm[ka + i][ra] = (k < K) ? A[(size_t)(row0 + ra) * K + k] : 0.f;
        }
#pragma unroll
        for (int j = 0; j < 4; ++j) {
            int k = k0 + kb;
            Bsm[kb][nb + j] = (k < K) ? W[(size_t)k * N + col0 + nb + j] : 0.f;
        }
        __syncthreads();
#pragma unroll
        for (int kk = 0; kk < BK; ++kk) {
            float a[4], b[4];
#pragma unroll
            for (int i = 0; i < 4; ++i) a[i] = Asm[kk][ty * 4 + i];
#pragma unroll
            for (int j = 0; j < 4; ++j) b[j] = Bsm[kk][tx * 4 + j];
#pragma unroll
            for (int i = 0; i < 4; ++i)
#pragma unroll
                for (int j = 0; j < 4; ++j) acc[i][j] += a[i] * b[j];
        }
        __syncthreads();
    }
#pragma unroll
    for (int i = 0; i < 4; ++i) {
        int rr = row0 + ty * 4 + i;
#pragma unroll
        for (int j = 0; j < 4; ++j) {
            int c = col0 + tx * 4 + j;
            float v = acc[i][j] + bias[c];
            if (act == 2) v = (v > 0.f) ? v : 0.01f * v;
            C[(size_t)rr * N + c] = v;
        }
    }
}

__global__ void gemv_out_kernel(const float* __restrict__ A, const float* __restrict__ w,
                                const float* __restrict__ b, float* __restrict__ out, int K) {
    int wave = threadIdx.x >> 6;
    int lane = threadIdx.x & 63;
    int row = blockIdx.x * 4 + wave;
    float acc = 0.f;
    for (int k = lane; k < K; k += 64) acc += A[(size_t)row * K + k] * w[k];
#pragma unroll
    for (int off = 32; off > 0; off >>= 1) acc += __shfl_down(acc, off, 64);
    if (lane == 0) out[row] = acc + b[0];
}

extern "C" void kernel_launch(void* const* d_in, const int* in_sizes, int n_in,
                              void* d_out, int out_size, void* d_ws, size_t ws_size,
                              hipStream_t stream) {
    const int*   cat_src = (const int*)d_in[0];
    const int*   cat_dst = (const int*)d_in[1];
    const float* cat_x   = (const float*)d_in[3];
    const int*   an_src  = (const int*)d_in[4];
    const int*   an_dst  = (const int*)d_in[5];
    const float* an_x    = (const float*)d_in[7];
    const float* add_f   = (const float*)d_in[8];
    const float* W0      = (const float*)d_in[9];
    const float* b0      = (const float*)d_in[10];
    const float* gcrW    = (const float*)d_in[11];
    const float* gcrb    = (const float*)d_in[12];
    const float* mW1     = (const float*)d_in[13];
    const float* mb1     = (const float*)d_in[14];
    const float* mW2     = (const float*)d_in[15];
    const float* mb2     = (const float*)d_in[16];
    const float* mW3     = (const float*)d_in[17];
    const float* mb3     = (const float*)d_in[18];
    float* out = (float*)d_out;

    // ---- workspace carve (~135 MB) ----
    char* p = (char*)d_ws;
    auto alloc = [&](size_t bytes) -> void* {
        void* rp = (void*)p;
        p += (bytes + 255) & ~(size_t)255;
        return rp;
    };
    int*   dego   = (int*)alloc((size_t)NN * 4);
    int*   cnti   = (int*)alloc((size_t)NN * 4);
    int*   bucket = (int*)alloc((size_t)NN * DEGCAP * 4);
    float* rso    = (float*)alloc((size_t)NN * 4);
    float* rsi    = (float*)alloc((size_t)NN * 4);
    u16*   aggx   = (u16*)alloc((size_t)NN * KPAD * 2);
    u16*   hA     = (u16*)alloc((size_t)NN * H * 2);
    u16*   hB     = (u16*)alloc((size_t)NN * H * 2);
    u16*   Wt0    = (u16*)alloc((size_t)H * KPAD * 2);
    u16*   Wtg    = (u16*)alloc((size_t)10 * H * H * 2);
    float* z      = (float*)alloc((size_t)NB * ZD * 4);
    float* m1     = (float*)alloc((size_t)NB * 1024 * 4);
    float* m2     = (float*)alloc((size_t)NB * 512 * 4);
    (void)ws_size; (void)in_sizes; (void)n_in; (void)out_size;

    // weight prep (bf16 transposed)
    prep_w0_kernel<<<(H * KPAD) / 256, 256, 0, stream>>>(W0, Wt0);
    prep_gcr_kernel<<<dim3(H * H / 256, 10), 256, 0, stream>>>(gcrW, Wtg);

    dim3 ggrid(NN / 128, H / 128);

    auto run_side = [&](const int* src, const int* dst, const float* x, int zoff) {
        hipMemsetAsync(dego, 0, (size_t)NN * 4, stream);
        hipMemsetAsync(cnti, 0, (size_t)NN * 4, stream);
        fill_kernel<<<(NE + 255) / 256, 256, 0, stream>>>(src, dst, dego, cnti, bucket);
        rsqrt_kernel<<<NN / 256, 256, 0, stream>>>(dego, cnti, rso, rsi);

        gather_x_kernel<<<NN, 128, 0, stream>>>(x, bucket, cnti, rso, rsi, aggx);
        gemm_mfma_kernel<<<ggrid, 256, 0, stream>>>(aggx, KPAD, Wt0, KPAD, b0, hA,
                                                    KPAD / 32, 0);
        for (int l = 0; l < 10; ++l) {
            gather_h_kernel<<<NN / 8, 256, 0, stream>>>(hA, bucket, cnti, rso, rsi, hB);
            gemm_mfma_kernel<<<ggrid, 256, 0, stream>>>(hB, H, Wtg + (size_t)l * H * H, H,
                                                        gcrb + (size_t)l * H, hA, H / 32, 1);
        }
        pool_kernel<<<NB, 256, 0, stream>>>(hA, z, zoff);
    };

    run_side(cat_src, cat_dst, cat_x, 0);
    run_side(an_src, an_dst, an_x, H);
    copy_add_kernel<<<(NB * 8 + 255) / 256, 256, 0, stream>>>(add_f, z);

    // MLP head (fp32)
    gemm_f32_kernel<<<dim3(NB / BM, 1024 / BN), 256, 0, stream>>>(z, mW1, mb1, m1,
                                                                  NB, 1024, ZD, 2);
    gemm_f32_kernel<<<dim3(NB / BM, 512 / BN), 256, 0, stream>>>(m1, mW2, mb2, m2,
                                                                 NB, 512, 1024, 2);
    gemv_out_kernel<<<NB / 4, 256, 0, stream>>>(m2, mW3, mb3, out, 512);
}